// Round 1
// 603.153 us; speedup vs baseline: 1.1184x; 1.1184x over previous
//
#include <hip/hip_runtime.h>
#include <hip/hip_bf16.h>

typedef __bf16 bf16;
typedef bf16 bf16x4 __attribute__((ext_vector_type(4)));
typedef bf16 bf16x8 __attribute__((ext_vector_type(8)));
typedef float f32x4 __attribute__((ext_vector_type(4)));

// LDS layout (short offsets), 24576 shorts = 48 KiB -> 3 blocks/CU.
// Phase A/B: [0,8192) x bf16 [128][64] swz | [8192,12288) WrT | [12288,16384) WqT
//            [16384,20480) WkT | [20480,24576) unused
// Phase B':  [8192,16384) per-wave scratch (2048 shorts each): Q-transpose, then A-tiles
// Phase C:   [0,8192) Krm [128][64] swz | [16384,24576) Kcm [64][128] swz
// All tiles XOR-swizzled: short_idx ^= (row & 7) << 3  (16B-granule bank spread,
// identical XOR on write and read sides -> <=2-way conflicts on ds_read_b128).
#define XS_OFF   0
#define W_OFF    8192
#define SCR_OFF  8192
#define KCM_OFF  16384

__device__ inline short f2bs(float v) { bf16 b = (bf16)v; return __builtin_bit_cast(short, b); }
__device__ inline bf16x8 ldfrag(const short* s) {
  uint4 u = *(const uint4*)s;
  return __builtin_bit_cast(bf16x8, u);
}
__device__ inline f32x4 mfma16(bf16x8 a, bf16x8 b, f32x4 c) {
  return __builtin_amdgcn_mfma_f32_16x16x32_bf16(a, b, c, 0, 0, 0);
}

__global__ __launch_bounds__(256, 3) void fused_mha_kernel(
    const float* __restrict__ x, const float* __restrict__ qw,
    const float* __restrict__ kw, const float* __restrict__ rw,
    const float* __restrict__ gamma, const float* __restrict__ beta,
    float* __restrict__ out)
{
  __shared__ __align__(16) short smem[24576];

  const int bx   = blockIdx.x;          // h*1024 + b (all 8 heads of b land on one XCD)
  const int h    = bx >> 10;
  const int b    = bx & 1023;
  const int tid  = threadIdx.x;
  const int w    = tid >> 6;            // wave 0..3; owns f-rows [32w, 32w+32)
  const int lane = tid & 63;
  const int q    = lane >> 4;
  const int l15  = lane & 15;
  const int fr0  = w * 32;
  const int swl  = (l15 & 7) << 3;      // row-swizzle term for rows of form k*16+l15 / k*8+l15

  // ---- Phase A: stage x (bf16, swizzled) and the three transposed weight tiles ----
  {
    const float4* xg = (const float4*)(x + (size_t)b * 8192);
#pragma unroll
    for (int r = 0; r < 8; ++r) {
      int idx4 = r * 256 + tid;             // 2048 float4s
      float4 v = xg[idx4];
      int f = idx4 >> 4;
      int i = (idx4 & 15) * 4;
      bf16x4 t;
      t[0] = (bf16)v.x; t[1] = (bf16)v.y; t[2] = (bf16)v.z; t[3] = (bf16)v.w;
      *(bf16x4*)(void*)&smem[XS_OFF + ((f * 64 + i) ^ ((f & 7) << 3))] = t;
    }
    const float* wsrc[3] = {rw, qw, kw};    // LDS order: WR, WQ, WK
    int wi = tid >> 2;                      // DIN row 0..63
    int dg = (tid & 3) * 16;                // d-group
#pragma unroll
    for (int s = 0; s < 3; ++s) {
      const float* base = wsrc[s] + (size_t)wi * 512 + h * 64 + dg;
      short* dst = smem + W_OFF + s * 4096;
#pragma unroll
      for (int u = 0; u < 4; ++u) {
        float4 v = *(const float4*)(base + u * 4);
        int d0 = dg + u * 4;
        dst[((d0 + 0) * 64 + wi) ^ (((d0 + 0) & 7) << 3)] = f2bs(v.x);
        dst[((d0 + 1) * 64 + wi) ^ (((d0 + 1) & 7) << 3)] = f2bs(v.y);
        dst[((d0 + 2) * 64 + wi) ^ (((d0 + 2) & 7) << 3)] = f2bs(v.z);
        dst[((d0 + 3) * 64 + wi) ^ (((d0 + 3) & 7) << 3)] = f2bs(v.w);
      }
    }
  }
  __syncthreads();   // barrier #1: staging complete

  // ---- Phase B: per-wave projections of own 32 rows (M=32, N=64, K=64; 16 MFMA each) ----
  auto proj = [&](int woff, f32x4* acc) {
#pragma unroll
    for (int t = 0; t < 8; ++t) acc[t] = (f32x4){0.f, 0.f, 0.f, 0.f};
#pragma unroll
    for (int ks = 0; ks < 2; ++ks) {
      int ke = ks * 32 + q * 8;
      bf16x8 a0 = ldfrag(&smem[XS_OFF + (((fr0 +      l15) * 64 + ke) ^ swl)]);
      bf16x8 a1 = ldfrag(&smem[XS_OFF + (((fr0 + 16 + l15) * 64 + ke) ^ swl)]);
#pragma unroll
      for (int nt = 0; nt < 4; ++nt) {
        bf16x8 bb = ldfrag(&smem[woff + (((nt * 16 + l15) * 64 + ke) ^ swl)]);
        acc[nt]     = mfma16(a0, bb, acc[nt]);
        acc[4 + nt] = mfma16(a1, bb, acc[4 + nt]);
      }
    }
  };

  // R = x*Wr -> global (raw output 2)
  {
    f32x4 racc[8];
    proj(W_OFF, racc);
    float* outR = out + 67108864 + (size_t)bx * 8192;
#pragma unroll
    for (int t = 0; t < 8; ++t) {
      int mt = t >> 2, nt = t & 3;
      int row0 = fr0 + mt * 16 + q * 4;
      int col  = nt * 16 + l15;
#pragma unroll
      for (int r = 0; r < 4; ++r) outR[(row0 + r) * 64 + col] = racc[t][r];
    }
  }

  f32x4 qacc[8]; proj(W_OFF + 4096, qacc);   // Q
  f32x4 kacc[8]; proj(W_OFF + 8192, kacc);   // K (== V)
  __syncthreads();   // barrier #2: all waves done reading x-tile and all W tiles

  short* scr = smem + SCR_OFF + w * 2048;    // wave-private scratch (over WR+WQ)

  // Q-transpose through wave-private scratch -> 16 VGPRs of A-fragments
  {
#pragma unroll
    for (int t = 0; t < 8; ++t) {
      int mt = t >> 2, nt = t & 3;
      int fro = mt * 16 + q * 4;             // row within wave tile 0..31
      int col = nt * 16 + l15;
#pragma unroll
      for (int r = 0; r < 4; ++r)
        scr[((fro + r) * 64 + col) ^ (((fro + r) & 7) << 3)] = f2bs(qacc[t][r]);
    }
  }
  // K -> Krm [g][d] (over x-tile) and Kcm [d][g] (over WK+tail)
#pragma unroll
  for (int t = 0; t < 8; ++t) {
    int mt = t >> 2, nt = t & 3;
    int g0 = fr0 + mt * 16 + q * 4;
    int d  = nt * 16 + l15;
#pragma unroll
    for (int r = 0; r < 4; ++r) {
      int g = g0 + r;
      short kb = f2bs(kacc[t][r]);
      smem[XS_OFF  + ((g * 64  + d) ^ ((g & 7) << 3))] = kb;
      smem[KCM_OFF + ((d * 128 + g) ^ ((d & 7) << 3))] = kb;
    }
  }
  // wave-local fence: scratch writes (cross-lane) must land before frag reads
  asm volatile("s_waitcnt lgkmcnt(0)" ::: "memory");
  __builtin_amdgcn_sched_barrier(0);
  bf16x8 qf[2][2];
#pragma unroll
  for (int mt = 0; mt < 2; ++mt)
#pragma unroll
    for (int ks = 0; ks < 2; ++ks)
      qf[mt][ks] = ldfrag(&scr[((mt * 16 + l15) * 64 + ks * 32 + q * 8) ^ swl]);

  float gam[4], bet[4];
#pragma unroll
  for (int j = 0; j < 4; ++j) { gam[j] = gamma[j * 16 + l15]; bet[j] = beta[j * 16 + l15]; }

  __syncthreads();   // barrier #3 (last): Krm/Kcm visible to all waves

  // ---- Phase C: per-wave, barrier-free. 2 chunks of 16 rows each. ----
  float* out0 = out + (size_t)bx * 8192;
#pragma unroll
  for (int c2 = 0; c2 < 2; ++c2) {
    // S = Q*K^T for rows fr0+16*c2 .. +16, all 128 cols (A-operand from registers)
    f32x4 sacc[8];
#pragma unroll
    for (int j = 0; j < 8; ++j) sacc[j] = (f32x4){0.f, 0.f, 0.f, 0.f};
#pragma unroll
    for (int ks = 0; ks < 2; ++ks) {
      int ke = ks * 32 + q * 8;
      bf16x8 aS = qf[c2][ks];
#pragma unroll
      for (int nt = 0; nt < 8; ++nt) {
        bf16x8 bS = ldfrag(&smem[XS_OFF + (((nt * 16 + l15) * 64 + ke) ^ swl)]);
        sacc[nt] = mfma16(aS, bS, sacc[nt]);
      }
    }
    // sigmoid(S/8) -> A tile [16][128] in wave-private scratch
#pragma unroll
    for (int nt = 0; nt < 8; ++nt) {
      int gcol = nt * 16 + l15;
#pragma unroll
      for (int r = 0; r < 4; ++r) {
        int fa = q * 4 + r;
        float e = __expf(-0.125f * sacc[nt][r]);
        float a = __builtin_amdgcn_rcpf(1.0f + e);
        scr[((fa * 128 + gcol) ^ ((fa & 7) << 3))] = f2bs(a);
      }
    }
    asm volatile("s_waitcnt lgkmcnt(0)" ::: "memory");
    __builtin_amdgcn_sched_barrier(0);
    // O = A*V (M=16, N=64, K=128)
    f32x4 oacc[4];
#pragma unroll
    for (int j = 0; j < 4; ++j) oacc[j] = (f32x4){0.f, 0.f, 0.f, 0.f};
#pragma unroll
    for (int ks = 0; ks < 4; ++ks) {
      int ke = ks * 32 + q * 8;
      bf16x8 aO = ldfrag(&scr[((l15 * 128 + ke) ^ swl)]);
#pragma unroll
      for (int j = 0; j < 4; ++j) {
        bf16x8 bO = ldfrag(&smem[KCM_OFF + (((j * 16 + l15) * 128 + ke) ^ swl)]);
        oacc[j] = mfma16(aO, bO, oacc[j]);
      }
    }
    // Register LayerNorm: row's 64 d-values live in this quad (4 regs x 16 lanes)
#pragma unroll
    for (int r = 0; r < 4; ++r) {
      float v0 = oacc[0][r], v1 = oacc[1][r], v2 = oacc[2][r], v3 = oacc[3][r];
      float s1 = v0 + v1 + v2 + v3;
      float s2 = v0 * v0 + v1 * v1 + v2 * v2 + v3 * v3;
      s1 += __shfl_xor(s1, 1);  s2 += __shfl_xor(s2, 1);
      s1 += __shfl_xor(s1, 2);  s2 += __shfl_xor(s2, 2);
      s1 += __shfl_xor(s1, 4);  s2 += __shfl_xor(s2, 4);
      s1 += __shfl_xor(s1, 8);  s2 += __shfl_xor(s2, 8);
      float mean = s1 * 0.015625f;
      float var  = s2 * 0.015625f - mean * mean;
      float rstd = rsqrtf(var + 1e-3f);
      int gf = fr0 + c2 * 16 + q * 4 + r;
      float* dst = out0 + gf * 64 + l15;
      dst[0]  = (v0 - mean) * rstd * gam[0] + bet[0];
      dst[16] = (v1 - mean) * rstd * gam[1] + bet[1];
      dst[32] = (v2 - mean) * rstd * gam[2] + bet[2];
      dst[48] = (v3 - mean) * rstd * gam[3] + bet[3];
    }
    // WAR on scratch across c2 iterations is safe: wave-local DS ops execute in order.
  }
}

extern "C" void kernel_launch(void* const* d_in, const int* in_sizes, int n_in,
                              void* d_out, int out_size, void* d_ws, size_t ws_size,
                              hipStream_t stream) {
  const float* x     = (const float*)d_in[0];
  const float* qw    = (const float*)d_in[1];
  const float* kw    = (const float*)d_in[2];
  const float* rw    = (const float*)d_in[3];
  const float* gamma = (const float*)d_in[4];
  const float* beta  = (const float*)d_in[5];
  float* out = (float*)d_out;
  fused_mha_kernel<<<dim3(8192), dim3(256), 0, stream>>>(x, qw, kw, rw, gamma, beta, out);
}